// Round 14
// baseline (587.944 us; speedup 1.0000x reference)
//
#include <hip/hip_runtime.h>

// Problem constants (fixed by reference)
constexpr int NROWS = 2048;
constexpr int NCOLS = 32000;
constexpr int NC4   = NCOLS / 4;   // 8000 float4 per row
constexpr int NMID  = 99;
constexpr int BLOCK = 512;         // 8 waves: 4 reader + 4 writer
constexpr int HALF  = 256;         // threads per role
constexpr int RWAVES = HALF / 64;  // 4 reader waves
constexpr int MAXC  = 16;          // candidate cap per row (expected ~0.5/row)
constexpr int PIPE  = 8;           // baseline reader pipeline depth

// asm-burst tiling: NC4 = 8000 = 3*2048 + 7*256 + 64
constexpr int CHUNK      = 8 * HALF;       // 2048 float4 per 8-burst chunk
constexpr int MAIN_CHUNKS= 3;
constexpr int TAIL7_BASE = MAIN_CHUNKS * CHUNK;          // 6144
constexpr int TAIL1_BASE = TAIL7_BASE + 7 * HALF;        // 7936
constexpr int TAIL1_N    = NC4 - TAIL1_BASE;             // 64

typedef float vfloat4 __attribute__((ext_vector_type(4)));

__device__ inline float waveSum(float v) {
    #pragma unroll
    for (int off = 32; off > 0; off >>= 1)
        v += __shfl_down(v, off, 64);
    return v;
}

// WITHIN-PROBE A/B (infra flaky; one bench must answer the MLP question):
//   calib_ab<true>  — rows [0,1024): inline-asm 8-deep load burst
//   calib_ab<false> — rows [1024,2048): R4 compiler-scheduled loop (VGPR 28,
//                     162 us full-grid reference)
// Separate dispatches -> rocprof gives per-variant dur_us / VGPR / HBM.
template<bool USE_ASM>
__global__ __launch_bounds__(BLOCK, 4) void calib_ab(
    const float* __restrict__ logits,
    const float* __restrict__ log_temperature,
    const float* __restrict__ iso_x,
    const float* __restrict__ iso_y,
    float* __restrict__ out,
    int row_base)
{
    __shared__ float s_red[RWAVES];
    __shared__ float s_S;
    __shared__ int   s_cnt;
    __shared__ int   s_col[MAXC];
    __shared__ float s_z[MAXC];

    const int tid = threadIdx.x;
    const int row = row_base + blockIdx.x;

    if (tid == 0) s_cnt = 0;   // ordered before use by barrier #1

    float c0 = -3.4e38f, c1 = -3.4e38f;
    int   j0 = 0, j1 = 0;

    if (tid < HALF) {
        // ---- READERS: pure load stream ----
        float T = expf(log_temperature[0]);
        T = fminf(fmaxf(T, 0.1f), 10.0f);
        const float rT = 1.0f / T;
        const int lane = tid & 63;
        const int wave = tid >> 6;

        const vfloat4* __restrict__ row4 =
            reinterpret_cast<const vfloat4*>(logits) + (size_t)row * NC4;

        float s0 = 0.0f, s1 = 0.0f;

        auto process = [&](const vfloat4& v, int idx) {
            const float za = v[0] * rT, zb = v[1] * rT;
            const float zc = v[2] * rT, zd = v[3] * rT;
            s0 += __expf(za) + __expf(zb);
            s1 += __expf(zc) + __expf(zd);
            const float qmax = fmaxf(fmaxf(za, zb), fmaxf(zc, zd));
            if (qmax > c1) {                       // rare, usually skipped
                const float zs[4] = {za, zb, zc, zd};
                #pragma unroll
                for (int k = 0; k < 4; ++k) {
                    const float zz = zs[k];
                    if (zz > c1) {
                        const int jj = idx * 4 + k;
                        if (zz > c0) { c1 = c0; j1 = j0; c0 = zz; j0 = jj; }
                        else         { c1 = zz; j1 = jj; }
                    }
                }
            }
        };

        if constexpr (USE_ASM) {
            // main: 3 chunks, each an asm burst of 8 back-to-back loads
            #pragma unroll
            for (int c = 0; c < MAIN_CHUNKS; ++c) {
                const int base = c * CHUNK + tid;
                const vfloat4* q = row4 + base;
                vfloat4 v0, v1, v2, v3, v4, v5, v6, v7;
                asm volatile(
                    "global_load_dwordx4 %[r0], %[p0], off\n\t"
                    "global_load_dwordx4 %[r1], %[p1], off\n\t"
                    "global_load_dwordx4 %[r2], %[p2], off\n\t"
                    "global_load_dwordx4 %[r3], %[p3], off\n\t"
                    "global_load_dwordx4 %[r4], %[p4], off\n\t"
                    "global_load_dwordx4 %[r5], %[p5], off\n\t"
                    "global_load_dwordx4 %[r6], %[p6], off\n\t"
                    "global_load_dwordx4 %[r7], %[p7], off\n\t"
                    "s_waitcnt vmcnt(0)"
                    : [r0]"=&v"(v0), [r1]"=&v"(v1), [r2]"=&v"(v2), [r3]"=&v"(v3),
                      [r4]"=&v"(v4), [r5]"=&v"(v5), [r6]"=&v"(v6), [r7]"=&v"(v7)
                    : [p0]"v"(q),            [p1]"v"(q + 1*HALF),
                      [p2]"v"(q + 2*HALF),   [p3]"v"(q + 3*HALF),
                      [p4]"v"(q + 4*HALF),   [p5]"v"(q + 5*HALF),
                      [p6]"v"(q + 6*HALF),   [p7]"v"(q + 7*HALF)
                    : "memory");
                __builtin_amdgcn_sched_barrier(0);
                process(v0, base + 0*HALF); process(v1, base + 1*HALF);
                process(v2, base + 2*HALF); process(v3, base + 3*HALF);
                process(v4, base + 4*HALF); process(v5, base + 5*HALF);
                process(v6, base + 6*HALF); process(v7, base + 7*HALF);
            }
            // tail: asm burst of 7
            {
                const int base = TAIL7_BASE + tid;
                const vfloat4* q = row4 + base;
                vfloat4 v0, v1, v2, v3, v4, v5, v6;
                asm volatile(
                    "global_load_dwordx4 %[r0], %[p0], off\n\t"
                    "global_load_dwordx4 %[r1], %[p1], off\n\t"
                    "global_load_dwordx4 %[r2], %[p2], off\n\t"
                    "global_load_dwordx4 %[r3], %[p3], off\n\t"
                    "global_load_dwordx4 %[r4], %[p4], off\n\t"
                    "global_load_dwordx4 %[r5], %[p5], off\n\t"
                    "global_load_dwordx4 %[r6], %[p6], off\n\t"
                    "s_waitcnt vmcnt(0)"
                    : [r0]"=&v"(v0), [r1]"=&v"(v1), [r2]"=&v"(v2), [r3]"=&v"(v3),
                      [r4]"=&v"(v4), [r5]"=&v"(v5), [r6]"=&v"(v6)
                    : [p0]"v"(q),            [p1]"v"(q + 1*HALF),
                      [p2]"v"(q + 2*HALF),   [p3]"v"(q + 3*HALF),
                      [p4]"v"(q + 4*HALF),   [p5]"v"(q + 5*HALF),
                      [p6]"v"(q + 6*HALF)
                    : "memory");
                __builtin_amdgcn_sched_barrier(0);
                process(v0, base + 0*HALF); process(v1, base + 1*HALF);
                process(v2, base + 2*HALF); process(v3, base + 3*HALF);
                process(v4, base + 4*HALF); process(v5, base + 5*HALF);
                process(v6, base + 6*HALF);
            }
            // last 64 float4: plain guarded load
            if (tid < TAIL1_N) {
                vfloat4 v = row4[TAIL1_BASE + tid];
                process(v, TAIL1_BASE + tid);
            }
        } else {
            // baseline: R4 guarded rolled loop (measured 162 us, VGPR 28)
            for (int base = tid; base < NC4; base += PIPE * HALF) {
                vfloat4 v[PIPE];
                #pragma unroll
                for (int u = 0; u < PIPE; ++u) {
                    const int idx = base + u * HALF;
                    if (idx < NC4) v[u] = row4[idx];
                }
                #pragma unroll
                for (int u = 0; u < PIPE; ++u) {
                    const int idx = base + u * HALF;
                    if (idx < NC4) process(v[u], idx);
                }
            }
        }

        float wsum = waveSum(s0 + s1);
        if (lane == 0) s_red[wave] = wsum;
    } else {
        // ---- WRITERS: fire-and-forget nontemporal fill (identical both variants) ----
        const float y0 = iso_y[0];
        const vfloat4 fill = {y0, y0, y0, y0};
        vfloat4* out4 = reinterpret_cast<vfloat4*>(out) + (size_t)row * NC4;
        for (int i = tid - HALF; i < NC4; i += HALF)
            __builtin_nontemporal_store(fill, &out4[i]);
    }

    __syncthreads();   // #1: fill stores ack'd (vmcnt 0); reader partials visible

    if (tid == 0) s_S = s_red[0] + s_red[1] + s_red[2] + s_red[3];
    __syncthreads();   // #2

    const float S     = s_S;
    const float mids0 = 0.5f * (iso_x[0] + iso_x[1]);
    const float zcut  = logf(mids0 * S) - 1e-4f;   // conservative candidate cut

    if (c0 >= zcut) {
        int p = atomicAdd(&s_cnt, 1);
        if (p < MAXC) { s_col[p] = j0; s_z[p] = c0; }
    }
    if (c1 >= zcut) {
        int p = atomicAdd(&s_cnt, 1);
        if (p < MAXC) { s_col[p] = j1; s_z[p] = c1; }
    }
    __syncthreads();   // #3

    const int cnt = min(s_cnt, MAXC);
    if (tid < cnt) {
        const int   col = s_col[tid];
        const float z   = s_z[tid];
        const float p   = expf(z) / S;            // precise exp + IEEE div
        int ii = 0;
        while (ii < NMID && 0.5f * (iso_x[ii] + iso_x[ii + 1]) < p) ++ii;
        out[(size_t)row * NCOLS + col] = iso_y[ii];
    }
}

extern "C" void kernel_launch(void* const* d_in, const int* in_sizes, int n_in,
                              void* d_out, int out_size, void* d_ws, size_t ws_size,
                              hipStream_t stream) {
    const float* logits = (const float*)d_in[0];
    const float* logT   = (const float*)d_in[1];
    const float* iso_x  = (const float*)d_in[2];
    const float* iso_y  = (const float*)d_in[3];
    float* out = (float*)d_out;
    (void)d_ws; (void)ws_size;

    constexpr int HALF_ROWS = NROWS / 2;
    calib_ab<true ><<<HALF_ROWS, BLOCK, 0, stream>>>(logits, logT, iso_x, iso_y,
                                                     out, 0);
    calib_ab<false><<<HALF_ROWS, BLOCK, 0, stream>>>(logits, logT, iso_x, iso_y,
                                                     out, HALF_ROWS);
}

// Round 17
// 567.348 us; speedup vs baseline: 1.0363x; 1.0363x over previous
//
#include <hip/hip_runtime.h>

// Problem constants (fixed by reference)
constexpr int NROWS = 2048;
constexpr int NCOLS = 32000;
constexpr int NC4   = NCOLS / 4;   // 8000 float4 per row
constexpr int NMID  = 99;
constexpr int BLOCK = 512;         // 8 waves: 4 reader + 4 writer
constexpr int HALF  = 256;         // threads per role
constexpr int RWAVES = HALF / 64;  // 4 reader waves
constexpr int MAXC  = 16;          // candidate cap per row

// Reader tiling: NC4 = 8000 = 3*2048 + 7*256 + 64
constexpr int CHUNK      = 8 * HALF;                     // 2048
constexpr int TAIL7_BASE = 3 * CHUNK;                    // 6144
constexpr int TAIL1_BASE = TAIL7_BASE + 7 * HALF;        // 7936
constexpr int TAIL1_N    = NC4 - TAIL1_BASE;             // 64

typedef float vfloat4 __attribute__((ext_vector_type(4)));

__device__ inline float waveSum(float v) {
    #pragma unroll
    for (int off = 32; off > 0; off >>= 1)
        v += __shfl_down(v, off, 64);
    return v;
}

// R14 lesson: burst + vmcnt(0) drain = 2x WORSE (165 us for half rows).
// Memory idled during compute, compute idled during loads. This round:
// COUNTED waits (T4) — issue bursts double-buffered, wait vmcnt(8/7), never
// drain to 0 mid-loop. 8-16 loads stay in flight per wave continuously.

__device__ __forceinline__ void issue8(const vfloat4* q,
    vfloat4& r0, vfloat4& r1, vfloat4& r2, vfloat4& r3,
    vfloat4& r4, vfloat4& r5, vfloat4& r6, vfloat4& r7)
{
    asm volatile(
        "global_load_dwordx4 %[r0], %[p0], off\n\t"
        "global_load_dwordx4 %[r1], %[p1], off\n\t"
        "global_load_dwordx4 %[r2], %[p2], off\n\t"
        "global_load_dwordx4 %[r3], %[p3], off\n\t"
        "global_load_dwordx4 %[r4], %[p4], off\n\t"
        "global_load_dwordx4 %[r5], %[p5], off\n\t"
        "global_load_dwordx4 %[r6], %[p6], off\n\t"
        "global_load_dwordx4 %[r7], %[p7], off"
        : [r0]"=&v"(r0), [r1]"=&v"(r1), [r2]"=&v"(r2), [r3]"=&v"(r3),
          [r4]"=&v"(r4), [r5]"=&v"(r5), [r6]"=&v"(r6), [r7]"=&v"(r7)
        : [p0]"v"(q),            [p1]"v"(q + 1*HALF),
          [p2]"v"(q + 2*HALF),   [p3]"v"(q + 3*HALF),
          [p4]"v"(q + 4*HALF),   [p5]"v"(q + 5*HALF),
          [p6]"v"(q + 6*HALF),   [p7]"v"(q + 7*HALF)
        : "memory");
}

__device__ __forceinline__ void issue7(const vfloat4* q,
    vfloat4& r0, vfloat4& r1, vfloat4& r2, vfloat4& r3,
    vfloat4& r4, vfloat4& r5, vfloat4& r6)
{
    asm volatile(
        "global_load_dwordx4 %[r0], %[p0], off\n\t"
        "global_load_dwordx4 %[r1], %[p1], off\n\t"
        "global_load_dwordx4 %[r2], %[p2], off\n\t"
        "global_load_dwordx4 %[r3], %[p3], off\n\t"
        "global_load_dwordx4 %[r4], %[p4], off\n\t"
        "global_load_dwordx4 %[r5], %[p5], off\n\t"
        "global_load_dwordx4 %[r6], %[p6], off"
        : [r0]"=&v"(r0), [r1]"=&v"(r1), [r2]"=&v"(r2), [r3]"=&v"(r3),
          [r4]"=&v"(r4), [r5]"=&v"(r5), [r6]"=&v"(r6)
        : [p0]"v"(q),            [p1]"v"(q + 1*HALF),
          [p2]"v"(q + 2*HALF),   [p3]"v"(q + 3*HALF),
          [p4]"v"(q + 4*HALF),   [p5]"v"(q + 5*HALF),
          [p6]"v"(q + 6*HALF)
        : "memory");
}

// Counted waits: empty asm ties the waited regs ("+v" dataflow edge) so uses
// can't hoist above; sched_barrier(0) fences the scheduler (rule #18).
__device__ __forceinline__ void wait8(
    vfloat4& r0, vfloat4& r1, vfloat4& r2, vfloat4& r3,
    vfloat4& r4, vfloat4& r5, vfloat4& r6, vfloat4& r7)
{
    asm volatile("s_waitcnt vmcnt(8)"
        : "+v"(r0), "+v"(r1), "+v"(r2), "+v"(r3),
          "+v"(r4), "+v"(r5), "+v"(r6), "+v"(r7) :: "memory");
    __builtin_amdgcn_sched_barrier(0);
}
__device__ __forceinline__ void wait7(
    vfloat4& r0, vfloat4& r1, vfloat4& r2, vfloat4& r3,
    vfloat4& r4, vfloat4& r5, vfloat4& r6, vfloat4& r7)
{
    asm volatile("s_waitcnt vmcnt(7)"
        : "+v"(r0), "+v"(r1), "+v"(r2), "+v"(r3),
          "+v"(r4), "+v"(r5), "+v"(r6), "+v"(r7) :: "memory");
    __builtin_amdgcn_sched_barrier(0);
}
__device__ __forceinline__ void wait0_7(
    vfloat4& r0, vfloat4& r1, vfloat4& r2, vfloat4& r3,
    vfloat4& r4, vfloat4& r5, vfloat4& r6)
{
    asm volatile("s_waitcnt vmcnt(0)"
        : "+v"(r0), "+v"(r1), "+v"(r2), "+v"(r3),
          "+v"(r4), "+v"(r5), "+v"(r6) :: "memory");
    __builtin_amdgcn_sched_barrier(0);
}

__global__ __launch_bounds__(BLOCK, 4) void calib_wavesplit(
    const float* __restrict__ logits,
    const float* __restrict__ log_temperature,
    const float* __restrict__ iso_x,
    const float* __restrict__ iso_y,
    float* __restrict__ out)
{
    __shared__ float s_red[RWAVES];
    __shared__ float s_S;
    __shared__ int   s_cnt;
    __shared__ int   s_col[MAXC];
    __shared__ float s_z[MAXC];

    const int tid = threadIdx.x;
    const int row = blockIdx.x;

    if (tid == 0) s_cnt = 0;   // ordered before use by barrier #1

    float c0 = -3.4e38f, c1 = -3.4e38f;
    int   j0 = 0, j1 = 0;

    if (tid < HALF) {
        // ---- READERS: double-buffered asm pipeline, counted vmcnt ----
        float T = expf(log_temperature[0]);
        T = fminf(fmaxf(T, 0.1f), 10.0f);
        const float rT = 1.0f / T;
        const int lane = tid & 63;
        const int wave = tid >> 6;

        const vfloat4* __restrict__ row4 =
            reinterpret_cast<const vfloat4*>(logits) + (size_t)row * NC4;

        float s0 = 0.0f, s1 = 0.0f;

        auto process = [&](const vfloat4& v, int idx) {
            const float za = v[0] * rT, zb = v[1] * rT;
            const float zc = v[2] * rT, zd = v[3] * rT;
            s0 += __expf(za) + __expf(zb);
            s1 += __expf(zc) + __expf(zd);
            const float qmax = fmaxf(fmaxf(za, zb), fmaxf(zc, zd));
            if (qmax > c1) {                       // rare, usually skipped
                const float zs[4] = {za, zb, zc, zd};
                #pragma unroll
                for (int k = 0; k < 4; ++k) {
                    const float zz = zs[k];
                    if (zz > c1) {
                        const int jj = idx * 4 + k;
                        if (zz > c0) { c1 = c0; j1 = j0; c0 = zz; j0 = jj; }
                        else         { c1 = zz; j1 = jj; }
                    }
                }
            }
        };

        // tail64 FIRST: its plain load fully retires (compiler auto-wait)
        // before the counted region starts -> vmcnt bookkeeping stays exact.
        if (tid < TAIL1_N) {
            vfloat4 v = row4[TAIL1_BASE + tid];
            process(v, TAIL1_BASE + tid);
        }

        const vfloat4* q0 = row4 + 0 * CHUNK + tid;
        const vfloat4* q1 = row4 + 1 * CHUNK + tid;
        const vfloat4* q2 = row4 + 2 * CHUNK + tid;
        const vfloat4* qt = row4 + TAIL7_BASE + tid;

        vfloat4 a0, a1, a2, a3, a4, a5, a6, a7;
        vfloat4 b0, b1, b2, b3, b4, b5, b6, b7;

        #define PROC8(x, base) \
            process(x##0, (base) + 0*HALF + tid); \
            process(x##1, (base) + 1*HALF + tid); \
            process(x##2, (base) + 2*HALF + tid); \
            process(x##3, (base) + 3*HALF + tid); \
            process(x##4, (base) + 4*HALF + tid); \
            process(x##5, (base) + 5*HALF + tid); \
            process(x##6, (base) + 6*HALF + tid); \
            process(x##7, (base) + 7*HALF + tid);
        #define PROC7(x, base) \
            process(x##0, (base) + 0*HALF + tid); \
            process(x##1, (base) + 1*HALF + tid); \
            process(x##2, (base) + 2*HALF + tid); \
            process(x##3, (base) + 3*HALF + tid); \
            process(x##4, (base) + 4*HALF + tid); \
            process(x##5, (base) + 5*HALF + tid); \
            process(x##6, (base) + 6*HALF + tid);

        issue8(q0, a0, a1, a2, a3, a4, a5, a6, a7);   // out: 8  (c0)
        issue8(q1, b0, b1, b2, b3, b4, b5, b6, b7);   // out: 16 (c0,c1)

        wait8(a0, a1, a2, a3, a4, a5, a6, a7);        // c0 done; c1 in flight
        PROC8(a, 0 * CHUNK);
        issue8(q2, a0, a1, a2, a3, a4, a5, a6, a7);   // out: 16 (c1,c2)

        wait8(b0, b1, b2, b3, b4, b5, b6, b7);        // c1 done; c2 in flight
        PROC8(b, 1 * CHUNK);
        issue7(qt, b0, b1, b2, b3, b4, b5, b6);       // out: 15 (c2,t7)

        wait7(a0, a1, a2, a3, a4, a5, a6, a7);        // c2 done; t7 in flight
        PROC8(a, 2 * CHUNK);

        wait0_7(b0, b1, b2, b3, b4, b5, b6);          // t7 done (epilogue drain)
        PROC7(b, TAIL7_BASE);

        #undef PROC8
        #undef PROC7

        float wsum = waveSum(s0 + s1);
        if (lane == 0) s_red[wave] = wsum;
    } else {
        // ---- WRITERS: fire-and-forget nontemporal fill (unchanged) ----
        const float y0 = iso_y[0];
        const vfloat4 fill = {y0, y0, y0, y0};
        vfloat4* out4 = reinterpret_cast<vfloat4*>(out) + (size_t)row * NC4;
        for (int i = tid - HALF; i < NC4; i += HALF)
            __builtin_nontemporal_store(fill, &out4[i]);
    }

    __syncthreads();   // #1: fill stores ack'd (vmcnt 0); reader partials visible

    if (tid == 0) s_S = s_red[0] + s_red[1] + s_red[2] + s_red[3];
    __syncthreads();   // #2

    const float S     = s_S;
    const float mids0 = 0.5f * (iso_x[0] + iso_x[1]);
    const float zcut  = logf(mids0 * S) - 1e-4f;   // conservative candidate cut

    if (c0 >= zcut) {
        int p = atomicAdd(&s_cnt, 1);
        if (p < MAXC) { s_col[p] = j0; s_z[p] = c0; }
    }
    if (c1 >= zcut) {
        int p = atomicAdd(&s_cnt, 1);
        if (p < MAXC) { s_col[p] = j1; s_z[p] = c1; }
    }
    __syncthreads();   // #3

    const int cnt = min(s_cnt, MAXC);
    if (tid < cnt) {
        const int   col = s_col[tid];
        const float z   = s_z[tid];
        const float p   = expf(z) / S;            // precise exp + IEEE div
        int ii = 0;
        while (ii < NMID && 0.5f * (iso_x[ii] + iso_x[ii + 1]) < p) ++ii;
        out[(size_t)row * NCOLS + col] = iso_y[ii];
    }
}

extern "C" void kernel_launch(void* const* d_in, const int* in_sizes, int n_in,
                              void* d_out, int out_size, void* d_ws, size_t ws_size,
                              hipStream_t stream) {
    const float* logits = (const float*)d_in[0];
    const float* logT   = (const float*)d_in[1];
    const float* iso_x  = (const float*)d_in[2];
    const float* iso_y  = (const float*)d_in[3];
    float* out = (float*)d_out;
    (void)d_ws; (void)ws_size;

    calib_wavesplit<<<NROWS, BLOCK, 0, stream>>>(logits, logT, iso_x, iso_y, out);
}

// Round 18
// 443.231 us; speedup vs baseline: 1.3265x; 1.2800x over previous
//
#include <hip/hip_runtime.h>

// Problem constants (fixed by reference)
constexpr int NROWS = 2048;
constexpr int NCOLS = 32000;
constexpr int NC4   = NCOLS / 4;   // 8000 float4 per row
constexpr int NMID  = 99;
constexpr int BLOCK = 512;         // 8 waves: 4 reader + 4 writer
constexpr int HALF  = 256;         // threads per role
constexpr int RWAVES = HALF / 64;  // 4 reader waves
constexpr int MAXC  = 16;          // candidate cap per row
constexpr int PIPE  = 8;           // reader pipeline depth (compiler-scheduled)

typedef float vfloat4 __attribute__((ext_vector_type(4)));

__device__ inline float waveSum(float v) {
    #pragma unroll
    for (int off = 32; off > 0; off >>= 1)
        v += __shfl_down(v, off, 64);
    return v;
}

// R14/R17 post-mortem: BOTH asm MLP variants lost to the compiler's 2-deep
// loop (drain-0: 2x worse; counted-vmcnt: 1.75x worse + scratch spills,
// VGPR=64 with FETCH+19MB/WRITE+50MB spill traffic). Per-wave issue depth is
// NOT the lever. New theory: streaming reads allocate in L1 and cap at its
// miss-queue depth (~3 wave-loads/CU in flight by Little's law) while stores
// bypass (fill=6.5 TB/s). Test: __builtin_nontemporal_load (nt -> L1 bypass,
// misses queue in L2). Within-probe A/B over row halves, single variable.
template<bool NT_LOAD>
__global__ __launch_bounds__(BLOCK, 4) void calib_ab(
    const float* __restrict__ logits,
    const float* __restrict__ log_temperature,
    const float* __restrict__ iso_x,
    const float* __restrict__ iso_y,
    float* __restrict__ out,
    int row_base)
{
    __shared__ float s_red[RWAVES];
    __shared__ float s_S;
    __shared__ int   s_cnt;
    __shared__ int   s_col[MAXC];
    __shared__ float s_z[MAXC];

    const int tid = threadIdx.x;
    const int row = row_base + blockIdx.x;

    if (tid == 0) s_cnt = 0;   // ordered before use by barrier #1

    float c0 = -3.4e38f, c1 = -3.4e38f;
    int   j0 = 0, j1 = 0;

    if (tid < HALF) {
        // ---- READERS: R4 rolled loop, compiler-scheduled (the 162 us best) ----
        float T = expf(log_temperature[0]);
        T = fminf(fmaxf(T, 0.1f), 10.0f);
        const float rT = 1.0f / T;
        const int lane = tid & 63;
        const int wave = tid >> 6;

        const vfloat4* __restrict__ row4 =
            reinterpret_cast<const vfloat4*>(logits) + (size_t)row * NC4;

        float s0 = 0.0f, s1 = 0.0f;

        for (int base = tid; base < NC4; base += PIPE * HALF) {
            vfloat4 v[PIPE];
            #pragma unroll
            for (int u = 0; u < PIPE; ++u) {
                const int idx = base + u * HALF;
                if (idx < NC4) {
                    if constexpr (NT_LOAD)
                        v[u] = __builtin_nontemporal_load(&row4[idx]);
                    else
                        v[u] = row4[idx];
                }
            }
            #pragma unroll
            for (int u = 0; u < PIPE; ++u) {
                const int idx = base + u * HALF;
                if (idx < NC4) {
                    const float za = v[u][0] * rT, zb = v[u][1] * rT;
                    const float zc = v[u][2] * rT, zd = v[u][3] * rT;
                    s0 += __expf(za) + __expf(zb);
                    s1 += __expf(zc) + __expf(zd);
                    const float qmax = fmaxf(fmaxf(za, zb), fmaxf(zc, zd));
                    if (qmax > c1) {                // rare, usually skipped
                        const float zs[4] = {za, zb, zc, zd};
                        #pragma unroll
                        for (int k = 0; k < 4; ++k) {
                            const float zz = zs[k];
                            if (zz > c1) {
                                const int jj = idx * 4 + k;
                                if (zz > c0) { c1 = c0; j1 = j0; c0 = zz; j0 = jj; }
                                else         { c1 = zz; j1 = jj; }
                            }
                        }
                    }
                }
            }
        }

        float wsum = waveSum(s0 + s1);
        if (lane == 0) s_red[wave] = wsum;
    } else {
        // ---- WRITERS: fire-and-forget nontemporal fill (identical both) ----
        const float y0 = iso_y[0];
        const vfloat4 fill = {y0, y0, y0, y0};
        vfloat4* out4 = reinterpret_cast<vfloat4*>(out) + (size_t)row * NC4;
        for (int i = tid - HALF; i < NC4; i += HALF)
            __builtin_nontemporal_store(fill, &out4[i]);
    }

    __syncthreads();   // #1: fill stores ack'd (vmcnt 0); reader partials visible

    if (tid == 0) s_S = s_red[0] + s_red[1] + s_red[2] + s_red[3];
    __syncthreads();   // #2

    const float S     = s_S;
    const float mids0 = 0.5f * (iso_x[0] + iso_x[1]);
    const float zcut  = logf(mids0 * S) - 1e-4f;   // conservative candidate cut

    if (c0 >= zcut) {
        int p = atomicAdd(&s_cnt, 1);
        if (p < MAXC) { s_col[p] = j0; s_z[p] = c0; }
    }
    if (c1 >= zcut) {
        int p = atomicAdd(&s_cnt, 1);
        if (p < MAXC) { s_col[p] = j1; s_z[p] = c1; }
    }
    __syncthreads();   // #3

    const int cnt = min(s_cnt, MAXC);
    if (tid < cnt) {
        const int   col = s_col[tid];
        const float z   = s_z[tid];
        const float p   = expf(z) / S;            // precise exp + IEEE div
        int ii = 0;
        while (ii < NMID && 0.5f * (iso_x[ii] + iso_x[ii + 1]) < p) ++ii;
        out[(size_t)row * NCOLS + col] = iso_y[ii];
    }
}

extern "C" void kernel_launch(void* const* d_in, const int* in_sizes, int n_in,
                              void* d_out, int out_size, void* d_ws, size_t ws_size,
                              hipStream_t stream) {
    const float* logits = (const float*)d_in[0];
    const float* logT   = (const float*)d_in[1];
    const float* iso_x  = (const float*)d_in[2];
    const float* iso_y  = (const float*)d_in[3];
    float* out = (float*)d_out;
    (void)d_ws; (void)ws_size;

    constexpr int HALF_ROWS = NROWS / 2;
    calib_ab<true ><<<HALF_ROWS, BLOCK, 0, stream>>>(logits, logT, iso_x, iso_y,
                                                     out, 0);          // nt loads
    calib_ab<false><<<HALF_ROWS, BLOCK, 0, stream>>>(logits, logT, iso_x, iso_y,
                                                     out, HALF_ROWS);  // plain
}